// Round 10
// baseline (196.156 us; speedup 1.0000x reference)
//
#include <hip/hip_runtime.h>
#include <hip/hip_cooperative_groups.h>
#include <math.h>

namespace cg = cooperative_groups;

// SpectralConv2d: fp16 split-precision MFMA GEMM phases.
// Round 9: single cooperative kernel {tables, fwd, mix, inv} with grid.sync
// between phases (kills 3 kernel-launch boundaries). Fallback = round-5
// 4-kernel path if cooperative launch is unavailable.
#define BB 16
#define CC 32
#define HH 256
#define WW 256
#define NIMG (BB * CC)  // 512

typedef _Float16 f16;
typedef __attribute__((ext_vector_type(8))) _Float16 f16x8;
typedef __attribute__((ext_vector_type(4))) float f32x4;

constexpr float TWO_PI_OVER_256 = 6.28318530717958647692f / 256.0f;

#define N_TWF 8192
#define N_ACOL 32768
#define N_AINV 16384
#define N_BINV 8192

static __device__ __forceinline__ f32x4 mfma3(f16x8 ah, f16x8 al, f16x8 bh,
                                              f16x8 bl, f32x4 c) {
  c = __builtin_amdgcn_mfma_f32_16x16x32_f16(ah, bh, c, 0, 0, 0);
  c = __builtin_amdgcn_mfma_f32_16x16x32_f16(ah, bl, c, 0, 0, 0);
  c = __builtin_amdgcn_mfma_f32_16x16x32_f16(al, bh, c, 0, 0, 0);
  return c;
}

static __device__ __forceinline__ void split16(float v, f16* hi, f16* lo) {
  f16 h_ = (f16)v;
  *hi = h_;
  *lo = (f16)(v - (float)h_);
}

// ---------------- table entry builder (shared by both paths) ----------------
static __device__ __forceinline__ void build_table(int id, f16* __restrict__ fb) {
  f16* twf_hi = fb;
  f16* twf_lo = twf_hi + N_TWF;
  f16* acol_hi = twf_lo + N_TWF;
  f16* acol_lo = acol_hi + N_ACOL;
  f16* ainv_hi = acol_lo + N_ACOL;
  f16* ainv_lo = ainv_hi + N_AINV;
  f16* binv_hi = ainv_lo + N_AINV;
  f16* binv_lo = binv_hi + N_BINV;

  float v;
  f16 *dh, *dl;
  if (id < N_TWF) {
    int idx = id;
    int j = idx & 7, lane = (idx >> 3) & 63, ks = (idx >> 9) & 7,
        nt = (idx >> 12) & 1;
    int col = nt * 16 + (lane & 15);
    int w = ks * 32 + ((lane >> 4) << 3) + j;
    int kx = col >> 1, ri = col & 1;
    int ph = (kx * w) & 255;
    float s, c;
    sincosf(TWO_PI_OVER_256 * (float)ph, &s, &c);
    v = ri ? -s : c;
    dh = twf_hi + idx;
    dl = twf_lo + idx;
  } else if (id < N_TWF + N_ACOL) {
    int idx = id - N_TWF;
    int j = idx & 7, lane = (idx >> 3) & 63, ks = (idx >> 9) & 7,
        mt = (idx >> 12) & 3, half = (idx >> 14) & 1;
    int row = mt * 16 + (lane & 15);
    int k = ks * 32 + ((lane >> 4) << 3) + j;
    int h = half * 128 + (k >> 1);
    int rj = k & 1;
    int zr = (row < 32) ? row : row - 32;
    int ky = (zr < 16) ? zr : 224 + zr;
    int ph = (ky * h) & 255;
    float s, c;
    sincosf(TWO_PI_OVER_256 * (float)ph, &s, &c);
    if (row < 32)
      v = rj ? s : c;
    else
      v = rj ? c : -s;
    dh = acol_hi + idx;
    dl = acol_lo + idx;
  } else if (id < N_TWF + N_ACOL + N_AINV) {
    int idx = id - N_TWF - N_ACOL;
    int j = idx & 7, lane = (idx >> 3) & 63, ks = (idx >> 9) & 1,
        mt = (idx >> 10) & 15;
    int h = mt * 16 + (lane & 15);
    int k = ks * 32 + ((lane >> 4) << 3) + j;
    int zr = k >> 1, rj = k & 1;
    int ky = (zr < 16) ? zr : 224 + zr;
    int ph = (ky * h) & 255;
    float s, c;
    sincosf(TWO_PI_OVER_256 * (float)ph, &s, &c);
    v = rj ? s : c;
    dh = ainv_hi + idx;
    dl = ainv_lo + idx;
  } else {
    int idx = id - N_TWF - N_ACOL - N_AINV;
    int j = idx & 7, lane = (idx >> 3) & 63, nt = (idx >> 9) & 15;
    int w = nt * 16 + (lane & 15);
    int k = ((lane >> 4) << 3) + j;
    int kx = k >> 1, ri = k & 1;
    int ph = (kx * w) & 255;
    float s, c;
    sincosf(TWO_PI_OVER_256 * (float)ph, &s, &c);
    float scale = ((kx == 0) ? 1.0f : 2.0f) / 65536.0f;
    v = ri ? -scale * s : scale * c;
    dh = binv_hi + idx;
    dl = binv_lo + idx;
  }
  f16 hi, lo;
  split16(v, &hi, &lo);
  *dh = hi;
  *dl = lo;
}

// ======================= cooperative all-in-one kernel ======================
__global__ __launch_bounds__(256) void k_all(const float* __restrict__ x,
                                             const float* __restrict__ w1,
                                             const float* __restrict__ w2,
                                             float* __restrict__ out,
                                             f16* __restrict__ fb,
                                             float* __restrict__ Zp,
                                             float* __restrict__ Og) {
  __shared__ __align__(16) char smem[81920];  // 80 KB union
  cg::grid_group grid = cg::this_grid();
  const int t = threadIdx.x, lane = t & 63, wid = t >> 6;
  const int l15 = lane & 15, kgrp = lane >> 4;
  const int bid = blockIdx.x, gD = gridDim.x;

  const f16* twf_hi = fb;
  const f16* twf_lo = twf_hi + N_TWF;
  const f16* acol_hi = twf_lo + N_TWF;
  const f16* acol_lo = acol_hi + N_ACOL;
  const f16* ainv_hi = acol_lo + N_ACOL;
  const f16* ainv_lo = ainv_hi + N_AINV;
  const f16* binv_hi = ainv_lo + N_AINV;
  const f16* binv_lo = binv_hi + N_BINV;

  // ---- phase 0: tables ----
  for (int task = bid; task < 256; task += gD) build_table(task * 256 + t, fb);
  grid.sync();

  // ---- phase F: forward ----
  {
    float* xs = (float*)smem;            // [2][32][256] = 64 KB
    char* ychb = smem + 65536;           // Yc_hi 8 KB
    char* yclb = smem + 73728;           // Yc_lo 8 KB
    const int mt = wid >> 1;
    const int nt = wid & 1;
    f16x8 tbh[8], tbl[8];
#pragma unroll
    for (int ks = 0; ks < 8; ++ks) {
      const int bo = ((nt * 8 + ks) * 64 + lane) * 8;
      tbh[ks] = *(const f16x8*)(twf_hi + bo);
      tbl[ks] = *(const f16x8*)(twf_lo + bo);
    }
    asm volatile("" ::: "memory");

    for (int task = bid; task < NIMG; task += gD) {
      const float* xim0 = x + (size_t)task * (HH * WW);
      for (int half = 0; half < 2; ++half) {
        const float* xim = xim0 + half * 128 * WW;
        auto STAGE = [&](int c, int b) {
#pragma unroll
          for (int i = 0; i < 8; ++i) {
            const int row = wid * 8 + i;
            const int go = (lane * 16) ^ ((row & 7) << 4);
            __builtin_amdgcn_global_load_lds(
                (const __attribute__((address_space(1))) void*)(xim + (c * 32 + row) * WW + (go >> 2)),
                (__attribute__((address_space(3))) void*)(xs + b * 8192 + row * 256),
                16, 0, 0);
          }
        };
        STAGE(0, 0);
        STAGE(1, 1);
#pragma unroll
        for (int c = 0; c < 4; ++c) {
          if (c == 3)
            asm volatile("s_waitcnt vmcnt(0)" ::: "memory");
          else
            asm volatile("s_waitcnt vmcnt(8)" ::: "memory");
          __builtin_amdgcn_s_barrier();
          {
            const int row = mt * 16 + l15;
            const char* rb = (const char*)(xs + (c & 1) * 8192 + row * 256);
            const int swz = (row & 7) << 4;
            f32x4 acc = {0.f, 0.f, 0.f, 0.f};
#pragma unroll
            for (int ks = 0; ks < 8; ++ks) {
              const int off = 128 * ks + 32 * kgrp;
              float4 a0 = *(const float4*)(rb + (off ^ swz));
              float4 a1 = *(const float4*)(rb + ((off + 16) ^ swz));
              float vv[8] = {a0.x, a0.y, a0.z, a0.w, a1.x, a1.y, a1.z, a1.w};
              f16x8 ah, al;
#pragma unroll
              for (int e = 0; e < 8; ++e) {
                f16 h_ = (f16)vv[e];
                ah[e] = h_;
                al[e] = (f16)(vv[e] - (float)h_);
              }
              acc = mfma3(ah, al, tbh[ks], tbl[ks], acc);
            }
            const int n = nt * 16 + l15;
            const int kx = n >> 1, ri = n & 1;
            char* yh = ychb + kx * 512;
            char* yl = yclb + kx * 512;
            const int kswz = (kx & 7) << 4;
#pragma unroll
            for (int jj = 0; jj < 4; ++jj) {
              const int hl = c * 32 + mt * 16 + kgrp * 4 + jj;
              const int boff = (4 * hl + 2 * ri) ^ kswz;
              float v = acc[jj];
              f16 hv = (f16)v;
              *(f16*)(yh + boff) = hv;
              *(f16*)(yl + boff) = (f16)(v - (float)hv);
            }
          }
          asm volatile("s_waitcnt lgkmcnt(0)" ::: "memory");
          __builtin_amdgcn_s_barrier();
          if (c < 2) STAGE(c + 2, c & 1);
        }
        // col phase
        f32x4 zacc = {0.f, 0.f, 0.f, 0.f};
        const int kswz2 = (l15 & 7) << 4;
        const char* ybh = ychb + l15 * 512;
        const char* ybl = yclb + l15 * 512;
#pragma unroll
        for (int ks = 0; ks < 8; ++ks) {
          const int ao = ((((half * 4 + wid) * 8) + ks) * 64 + lane) * 8;
          f16x8 a_h = *(const f16x8*)(acol_hi + ao);
          f16x8 a_l = *(const f16x8*)(acol_lo + ao);
          const int boff = (64 * ks + 16 * kgrp) ^ kswz2;
          f16x8 b_h = *(const f16x8*)(ybh + boff);
          f16x8 b_l = *(const f16x8*)(ybl + boff);
          zacc = mfma3(a_h, a_l, b_h, b_l, zacc);
        }
        float* zp = Zp + ((size_t)task * 2 + half) * 1024;
#pragma unroll
        for (int jj = 0; jj < 4; ++jj) {
          const int row = wid * 16 + kgrp * 4 + jj;
          zp[row * 16 + l15] = zacc[jj];
        }
      }
    }
  }
  grid.sync();

  // ---- phase M: channel mix ----
  {
    float* zsr = (float*)smem;          // [32][16]
    float* zsi = (float*)(smem + 2048); // [32][16]
    for (int task = bid; task < 512; task += gD) {
      const int b = task >> 5;
      const int zr = task & 31;
      const int kyi = zr & 15;
      const float* wsrc = (zr < 16) ? w1 : w2;
      {
        const int i = t >> 3, reim = (t >> 2) & 1, f4 = t & 3;
        const float* base = Zp + ((size_t)(b * CC + i) * 2) * 1024 +
                            reim * 512 + zr * 16 + f4 * 4;
        float4 a = *(const float4*)(base);
        float4 c = *(const float4*)(base + 1024);
        float4 s = make_float4(a.x + c.x, a.y + c.y, a.z + c.z, a.w + c.w);
        if (reim == 0)
          *(float4*)&zsr[i * 16 + f4 * 4] = s;
        else
          *(float4*)&zsi[i * 16 + f4 * 4] = s;
      }
      __syncthreads();
      const int kx = t & 15;
      const int oc0 = t >> 4;
      const float2* cp = (const float2*)wsrc;
#pragma unroll
      for (int pass = 0; pass < 2; ++pass) {
        const int oc = oc0 + pass * 16;
        float acc_r = 0.f, acc_i = 0.f;
#pragma unroll 4
        for (int i = 0; i < CC; ++i) {
          float zre = zsr[i * 16 + kx];
          float zim = zsi[i * 16 + kx];
          float2 cv = cp[(size_t)(i * CC + oc) * 256 + kyi * 16 + kx];
          acc_r += zre * cv.x - zim * cv.y;
          acc_i += zre * cv.y + zim * cv.x;
        }
        float2* dst = (float2*)Og + (size_t)(b * CC + oc) * 512 + zr * 16 + kx;
        *dst = make_float2(acc_r, acc_i);
      }
      __syncthreads();
    }
  }
  grid.sync();

  // ---- phase I: inverse ----
  {
    float* Olds = (float*)smem;              // 4 KB
    f16* T_hi = (f16*)(smem + 4096);         // 10240 B [128][40]
    f16* T_lo = (f16*)(smem + 14336);        // 10240 B
    f16* Bf_hi = (f16*)(smem + 24576);       // 4096 B
    f16* Bf_lo = (f16*)(smem + 28672);       // 4096 B
    for (int task = bid; task < NIMG; task += gD) {
      {
        float4 v = ((const float4*)(Og + (size_t)task * 1024))[t];
        *(float4*)&Olds[t * 4] = v;
      }
      __syncthreads();
#pragma unroll
      for (int e = 0; e < 8; ++e) {
        const int idx = e * 256 + t;
        const int nt = idx >> 10, ks = (idx >> 9) & 1, ln = (idx >> 3) & 63,
                  j = idx & 7;
        const int k = ks * 32 + ((ln >> 4) << 3) + j;
        const int n = nt * 16 + (ln & 15);
        const int zr = k >> 1, rj = k & 1, kx = n >> 1, ri = n & 1;
        const float Or = Olds[(zr * 16 + kx) * 2];
        const float Oi = Olds[(zr * 16 + kx) * 2 + 1];
        const float v = (rj == 0) ? (ri == 0 ? Or : Oi) : (ri == 0 ? -Oi : Or);
        f16 hv = (f16)v;
        Bf_hi[idx] = hv;
        Bf_lo[idx] = (f16)(v - (float)hv);
      }
      __syncthreads();
      for (int half = 0; half < 2; ++half) {
#pragma unroll
        for (int mm = 0; mm < 2; ++mm) {
          const int mtl = wid * 2 + mm;
          const int mt = half * 8 + mtl;
          f32x4 acc0 = {0.f, 0.f, 0.f, 0.f}, acc1 = {0.f, 0.f, 0.f, 0.f};
#pragma unroll
          for (int ks = 0; ks < 2; ++ks) {
            const int ao = ((mt * 2 + ks) * 64 + lane) * 8;
            f16x8 a_h = *(const f16x8*)(ainv_hi + ao);
            f16x8 a_l = *(const f16x8*)(ainv_lo + ao);
            const int bo0 = ((0 * 2 + ks) * 64 + lane) * 8;
            const int bo1 = ((1 * 2 + ks) * 64 + lane) * 8;
            f16x8 b0h = *(const f16x8*)(Bf_hi + bo0);
            f16x8 b0l = *(const f16x8*)(Bf_lo + bo0);
            f16x8 b1h = *(const f16x8*)(Bf_hi + bo1);
            f16x8 b1l = *(const f16x8*)(Bf_lo + bo1);
            acc0 = mfma3(a_h, a_l, b0h, b0l, acc0);
            acc1 = mfma3(a_h, a_l, b1h, b1l, acc1);
          }
#pragma unroll
          for (int nt = 0; nt < 2; ++nt) {
#pragma unroll
            for (int jj = 0; jj < 4; ++jj) {
              const int hl = mtl * 16 + kgrp * 4 + jj;
              const int n = nt * 16 + l15;
              float v = (nt == 0) ? acc0[jj] : acc1[jj];
              f16 hv = (f16)v;
              T_hi[hl * 40 + n] = hv;
              T_lo[hl * 40 + n] = (f16)(v - (float)hv);
            }
          }
        }
        __syncthreads();
        float* op = out + (size_t)task * (HH * WW) + (size_t)half * 128 * WW;
#pragma unroll
        for (int mm = 0; mm < 2; ++mm) {
          const int mtl = wid * 2 + mm;
          const int ao = (mtl * 16 + l15) * 40 + kgrp * 8;
          f16x8 a_h = *(const f16x8*)(T_hi + ao);
          f16x8 a_l = *(const f16x8*)(T_lo + ao);
#pragma unroll 4
          for (int nt = 0; nt < 16; ++nt) {
            const int bo = (nt * 64 + lane) * 8;
            f16x8 b_h = *(const f16x8*)(binv_hi + bo);
            f16x8 b_l = *(const f16x8*)(binv_lo + bo);
            f32x4 acc = {0.f, 0.f, 0.f, 0.f};
            acc = mfma3(a_h, a_l, b_h, b_l, acc);
#pragma unroll
            for (int jj = 0; jj < 4; ++jj) {
              const int hl = mtl * 16 + kgrp * 4 + jj;
              op[(size_t)hl * WW + nt * 16 + l15] = acc[jj];
            }
          }
        }
        __syncthreads();
      }
    }
  }
}

// ======================= round-5 fallback kernels ==========================
__global__ __launch_bounds__(256) void k_tw(f16* __restrict__ fb) {
  build_table(blockIdx.x * 256 + threadIdx.x, fb);
}

__global__ __launch_bounds__(256) void k_fwd(const float* __restrict__ x,
                                             const f16* __restrict__ twf_hi,
                                             const f16* __restrict__ twf_lo,
                                             const f16* __restrict__ acol_hi,
                                             const f16* __restrict__ acol_lo,
                                             float* __restrict__ Zp) {
  __shared__ __align__(16) float xs[2][32][256];
  __shared__ __align__(16) f16 Yc_hi[16 * 256];
  __shared__ __align__(16) f16 Yc_lo[16 * 256];
  const int t = threadIdx.x, lane = t & 63, wid = t >> 6;
  const int l15 = lane & 15, kgrp = lane >> 4;
  const int img = blockIdx.x >> 1;
  const int half = blockIdx.x & 1;
  const float* xim = x + (size_t)img * (HH * WW) + half * 128 * WW;
  const int mt = wid >> 1;
  const int nt = wid & 1;

  f16x8 tbh[8], tbl[8];
#pragma unroll
  for (int ks = 0; ks < 8; ++ks) {
    const int bo = ((nt * 8 + ks) * 64 + lane) * 8;
    tbh[ks] = *(const f16x8*)(twf_hi + bo);
    tbl[ks] = *(const f16x8*)(twf_lo + bo);
  }
  asm volatile("" ::: "memory");

  auto STAGE = [&](int c, int b) {
#pragma unroll
    for (int i = 0; i < 8; ++i) {
      const int row = wid * 8 + i;
      const int go = (lane * 16) ^ ((row & 7) << 4);
      __builtin_amdgcn_global_load_lds(
          (const __attribute__((address_space(1))) void*)(xim + (c * 32 + row) * WW + (go >> 2)),
          (__attribute__((address_space(3))) void*)&xs[b][row][0], 16, 0, 0);
    }
  };

  STAGE(0, 0);
  STAGE(1, 1);

#pragma unroll
  for (int c = 0; c < 4; ++c) {
    if (c == 3)
      asm volatile("s_waitcnt vmcnt(0)" ::: "memory");
    else
      asm volatile("s_waitcnt vmcnt(8)" ::: "memory");
    __builtin_amdgcn_s_barrier();
    {
      const int row = mt * 16 + l15;
      const char* rb = (const char*)&xs[c & 1][row][0];
      const int swz = (row & 7) << 4;
      f32x4 acc = {0.f, 0.f, 0.f, 0.f};
#pragma unroll
      for (int ks = 0; ks < 8; ++ks) {
        const int off = 128 * ks + 32 * kgrp;
        float4 a0 = *(const float4*)(rb + (off ^ swz));
        float4 a1 = *(const float4*)(rb + ((off + 16) ^ swz));
        float vv[8] = {a0.x, a0.y, a0.z, a0.w, a1.x, a1.y, a1.z, a1.w};
        f16x8 ah, al;
#pragma unroll
        for (int e = 0; e < 8; ++e) {
          f16 h_ = (f16)vv[e];
          ah[e] = h_;
          al[e] = (f16)(vv[e] - (float)h_);
        }
        acc = mfma3(ah, al, tbh[ks], tbl[ks], acc);
      }
      const int n = nt * 16 + l15;
      const int kx = n >> 1, ri = n & 1;
      char* yh = (char*)Yc_hi + kx * 512;
      char* yl = (char*)Yc_lo + kx * 512;
      const int kswz = (kx & 7) << 4;
#pragma unroll
      for (int jj = 0; jj < 4; ++jj) {
        const int hl = c * 32 + mt * 16 + kgrp * 4 + jj;
        const int boff = (4 * hl + 2 * ri) ^ kswz;
        float v = acc[jj];
        f16 hv = (f16)v;
        *(f16*)(yh + boff) = hv;
        *(f16*)(yl + boff) = (f16)(v - (float)hv);
      }
    }
    asm volatile("s_waitcnt lgkmcnt(0)" ::: "memory");
    __builtin_amdgcn_s_barrier();
    if (c < 2) STAGE(c + 2, c & 1);
  }

  f32x4 zacc = {0.f, 0.f, 0.f, 0.f};
  const int kswz2 = (l15 & 7) << 4;
  const char* ybh = (const char*)Yc_hi + l15 * 512;
  const char* ybl = (const char*)Yc_lo + l15 * 512;
#pragma unroll
  for (int ks = 0; ks < 8; ++ks) {
    const int ao = ((((half * 4 + wid) * 8) + ks) * 64 + lane) * 8;
    f16x8 a_h = *(const f16x8*)(acol_hi + ao);
    f16x8 a_l = *(const f16x8*)(acol_lo + ao);
    const int boff = (64 * ks + 16 * kgrp) ^ kswz2;
    f16x8 b_h = *(const f16x8*)(ybh + boff);
    f16x8 b_l = *(const f16x8*)(ybl + boff);
    zacc = mfma3(a_h, a_l, b_h, b_l, zacc);
  }
  float* zp = Zp + ((size_t)img * 2 + half) * 1024;
#pragma unroll
  for (int jj = 0; jj < 4; ++jj) {
    const int row = wid * 16 + kgrp * 4 + jj;
    zp[row * 16 + l15] = zacc[jj];
  }
}

__global__ __launch_bounds__(256) void k_mix(const float* __restrict__ Zp,
                                             const float* __restrict__ w1,
                                             const float* __restrict__ w2,
                                             float* __restrict__ O) {
  __shared__ float zsr[CC][16];
  __shared__ float zsi[CC][16];
  const int t = threadIdx.x;
  const int b = blockIdx.x >> 5;
  const int zr = blockIdx.x & 31;
  const int kyi = zr & 15;
  const float* wsrc = (zr < 16) ? w1 : w2;
  {
    const int i = t >> 3, reim = (t >> 2) & 1, f4 = t & 3;
    const float* base = Zp + ((size_t)(b * CC + i) * 2) * 1024 + reim * 512 +
                        zr * 16 + f4 * 4;
    float4 a = *(const float4*)(base);
    float4 c = *(const float4*)(base + 1024);
    float4 s = make_float4(a.x + c.x, a.y + c.y, a.z + c.z, a.w + c.w);
    if (reim == 0)
      *(float4*)&zsr[i][f4 * 4] = s;
    else
      *(float4*)&zsi[i][f4 * 4] = s;
  }
  __syncthreads();
  const int kx = t & 15;
  const int oc0 = t >> 4;
  const float2* cp = (const float2*)wsrc;
#pragma unroll
  for (int pass = 0; pass < 2; ++pass) {
    const int oc = oc0 + pass * 16;
    float acc_r = 0.f, acc_i = 0.f;
#pragma unroll 4
    for (int i = 0; i < CC; ++i) {
      float zre = zsr[i][kx];
      float zim = zsi[i][kx];
      float2 cv = cp[(size_t)(i * CC + oc) * 256 + kyi * 16 + kx];
      acc_r += zre * cv.x - zim * cv.y;
      acc_i += zre * cv.y + zim * cv.x;
    }
    float2* dst = (float2*)O + (size_t)(b * CC + oc) * 512 + zr * 16 + kx;
    *dst = make_float2(acc_r, acc_i);
  }
}

__global__ __launch_bounds__(256) void k_inv(const float* __restrict__ O,
                                             const f16* __restrict__ ainv_hi,
                                             const f16* __restrict__ ainv_lo,
                                             const f16* __restrict__ binv_hi,
                                             const f16* __restrict__ binv_lo,
                                             float* __restrict__ out) {
  __shared__ float Olds[1024];
  __shared__ __align__(16) f16 Bf_hi[2048], Bf_lo[2048];
  __shared__ __align__(16) f16 T_hi[128 * 40], T_lo[128 * 40];
  const int t = threadIdx.x, lane = t & 63, wid = t >> 6;
  const int l15 = lane & 15, kgrp = lane >> 4;
  const int img = blockIdx.x >> 1;
  const int half = blockIdx.x & 1;
  {
    float4 v = ((const float4*)(O + (size_t)img * 1024))[t];
    *(float4*)&Olds[t * 4] = v;
  }
  __syncthreads();
#pragma unroll
  for (int e = 0; e < 8; ++e) {
    const int idx = e * 256 + t;
    const int nt = idx >> 10, ks = (idx >> 9) & 1, ln = (idx >> 3) & 63,
              j = idx & 7;
    const int k = ks * 32 + ((ln >> 4) << 3) + j;
    const int n = nt * 16 + (ln & 15);
    const int zr = k >> 1, rj = k & 1, kx = n >> 1, ri = n & 1;
    const float Or = Olds[(zr * 16 + kx) * 2];
    const float Oi = Olds[(zr * 16 + kx) * 2 + 1];
    const float v = (rj == 0) ? (ri == 0 ? Or : Oi) : (ri == 0 ? -Oi : Or);
    f16 hv = (f16)v;
    Bf_hi[idx] = hv;
    Bf_lo[idx] = (f16)(v - (float)hv);
  }
  __syncthreads();
#pragma unroll
  for (int mm = 0; mm < 2; ++mm) {
    const int mtl = wid * 2 + mm;
    const int mt = half * 8 + mtl;
    f32x4 acc0 = {0.f, 0.f, 0.f, 0.f}, acc1 = {0.f, 0.f, 0.f, 0.f};
#pragma unroll
    for (int ks = 0; ks < 2; ++ks) {
      const int ao = ((mt * 2 + ks) * 64 + lane) * 8;
      f16x8 a_h = *(const f16x8*)(ainv_hi + ao);
      f16x8 a_l = *(const f16x8*)(ainv_lo + ao);
      const int bo0 = ((0 * 2 + ks) * 64 + lane) * 8;
      const int bo1 = ((1 * 2 + ks) * 64 + lane) * 8;
      f16x8 b0h = *(const f16x8*)(Bf_hi + bo0);
      f16x8 b0l = *(const f16x8*)(Bf_lo + bo0);
      f16x8 b1h = *(const f16x8*)(Bf_hi + bo1);
      f16x8 b1l = *(const f16x8*)(Bf_lo + bo1);
      acc0 = mfma3(a_h, a_l, b0h, b0l, acc0);
      acc1 = mfma3(a_h, a_l, b1h, b1l, acc1);
    }
#pragma unroll
    for (int nt = 0; nt < 2; ++nt) {
#pragma unroll
      for (int jj = 0; jj < 4; ++jj) {
        const int hl = mtl * 16 + kgrp * 4 + jj;
        const int n = nt * 16 + l15;
        float v = (nt == 0) ? acc0[jj] : acc1[jj];
        f16 hv = (f16)v;
        T_hi[hl * 40 + n] = hv;
        T_lo[hl * 40 + n] = (f16)(v - (float)hv);
      }
    }
  }
  __syncthreads();
  float* op = out + (size_t)img * (HH * WW) + (size_t)half * 128 * WW;
#pragma unroll
  for (int mm = 0; mm < 2; ++mm) {
    const int mtl = wid * 2 + mm;
    const int ao = (mtl * 16 + l15) * 40 + kgrp * 8;
    f16x8 a_h = *(const f16x8*)(T_hi + ao);
    f16x8 a_l = *(const f16x8*)(T_lo + ao);
#pragma unroll 4
    for (int nt = 0; nt < 16; ++nt) {
      const int bo = (nt * 64 + lane) * 8;
      f16x8 b_h = *(const f16x8*)(binv_hi + bo);
      f16x8 b_l = *(const f16x8*)(binv_lo + bo);
      f32x4 acc = {0.f, 0.f, 0.f, 0.f};
      acc = mfma3(a_h, a_l, b_h, b_l, acc);
#pragma unroll
      for (int jj = 0; jj < 4; ++jj) {
        const int hl = mtl * 16 + kgrp * 4 + jj;
        op[(size_t)hl * WW + nt * 16 + l15] = acc[jj];
      }
    }
  }
}

extern "C" void kernel_launch(void* const* d_in, const int* in_sizes, int n_in,
                              void* d_out, int out_size, void* d_ws,
                              size_t ws_size, hipStream_t stream) {
  const float* x = (const float*)d_in[0];
  const float* w1 = (const float*)d_in[1];
  const float* w2 = (const float*)d_in[2];
  float* out = (float*)d_out;

  f16* fb = (f16*)d_ws;
  f16* twf_hi = fb;
  f16* twf_lo = twf_hi + N_TWF;
  f16* acol_hi = twf_lo + N_TWF;
  f16* acol_lo = acol_hi + N_ACOL;
  f16* ainv_hi = acol_lo + N_ACOL;
  f16* ainv_lo = ainv_hi + N_AINV;
  f16* binv_hi = ainv_lo + N_AINV;
  f16* binv_lo = binv_hi + N_BINV;
  float* Zp = (float*)(binv_lo + N_BINV);  // 4 MB
  float* O = Zp + (size_t)NIMG * 2048;     // 2 MB

  // Size the cooperative grid from the occupancy query (deterministic).
  int maxb = 0;
  hipError_t qerr =
      hipOccupancyMaxActiveBlocksPerMultiprocessor(&maxb, k_all, 256, 0);
  int grid = 512;
  if (qerr == hipSuccess && maxb >= 1) {
    int cap = maxb * 256;  // 256 CUs
    if (cap < grid) grid = cap;
  }
  void* args[] = {(void*)&x, (void*)&w1, (void*)&w2, (void*)&out,
                  (void*)&fb, (void*)&Zp, (void*)&O};
  hipError_t lerr = hipLaunchCooperativeKernel((void*)k_all, dim3(grid),
                                               dim3(256), args, 0, stream);
  if (lerr != hipSuccess) {
    // Fallback: round-5 4-kernel path.
    k_tw<<<dim3(256), dim3(256), 0, stream>>>(fb);
    k_fwd<<<dim3(NIMG * 2), dim3(256), 0, stream>>>(x, twf_hi, twf_lo, acol_hi,
                                                    acol_lo, Zp);
    k_mix<<<dim3(BB * 32), dim3(256), 0, stream>>>(Zp, w1, w2, O);
    k_inv<<<dim3(NIMG * 2), dim3(256), 0, stream>>>(O, ainv_hi, ainv_lo,
                                                    binv_hi, binv_lo, out);
  }
}

// Round 11
// 74.935 us; speedup vs baseline: 2.6177x; 2.6177x over previous
//
#include <hip/hip_runtime.h>
#include <math.h>

// SpectralConv2d: all DFT stages as fp16 split-precision MFMA GEMMs.
// B=16, CIN=COUT=32, H=W=256, modes 16x16 (32 ky rows x 16 kx).
// Round 10: exact round-5 revert (best known, 77.3us) + k_mix oc-pass split
// (1024 blocks, halves k_mix critical path). Nothing else changed.
#define BB 16
#define CC 32
#define HH 256
#define WW 256
#define NIMG (BB * CC)  // 512

typedef _Float16 f16;
typedef __attribute__((ext_vector_type(8))) _Float16 f16x8;
typedef __attribute__((ext_vector_type(4))) float f32x4;

constexpr float TWO_PI_OVER_256 = 6.28318530717958647692f / 256.0f;

// ws layout (f16 element counts for the fragment tables):
//  TwF  (fwd-row  B frags) [nt2][ks8][lane64][j8]          = 8192
//  AcolF(fwd-col  A frags) [half2][mt4][ks8][lane64][j8]   = 32768
//  AinvF(inv-col  A frags) [mt16][ks2][lane64][j8]         = 16384
//  BinvF(inv-row  B frags) [nt16][lane64][j8]              = 8192
#define N_TWF 8192
#define N_ACOL 32768
#define N_AINV 16384
#define N_BINV 8192

static __device__ __forceinline__ f32x4 mfma3(f16x8 ah, f16x8 al, f16x8 bh,
                                              f16x8 bl, f32x4 c) {
  c = __builtin_amdgcn_mfma_f32_16x16x32_f16(ah, bh, c, 0, 0, 0);
  c = __builtin_amdgcn_mfma_f32_16x16x32_f16(ah, bl, c, 0, 0, 0);
  c = __builtin_amdgcn_mfma_f32_16x16x32_f16(al, bh, c, 0, 0, 0);
  return c;
}

static __device__ __forceinline__ void split16(float v, f16* hi, f16* lo) {
  f16 h_ = (f16)v;
  *hi = h_;
  *lo = (f16)(v - (float)h_);
}

// ---------------- k_tw: build twiddle fragment tables ----------------
__global__ __launch_bounds__(256) void k_tw(f16* __restrict__ fb) {
  const int id = blockIdx.x * 256 + threadIdx.x;  // 0..65535
  f16* twf_hi = fb;
  f16* twf_lo = twf_hi + N_TWF;
  f16* acol_hi = twf_lo + N_TWF;
  f16* acol_lo = acol_hi + N_ACOL;
  f16* ainv_hi = acol_lo + N_ACOL;
  f16* ainv_lo = ainv_hi + N_AINV;
  f16* binv_hi = ainv_lo + N_AINV;
  f16* binv_lo = binv_hi + N_BINV;

  float v;
  f16 *dh, *dl;
  if (id < N_TWF) {
    // fwd-row B[w][n]: n=2kx+ri: ri==0 -> cos(2pi kx w/256), ri==1 -> -sin
    int idx = id;
    int j = idx & 7, lane = (idx >> 3) & 63, ks = (idx >> 9) & 7,
        nt = (idx >> 12) & 1;
    int col = nt * 16 + (lane & 15);
    int w = ks * 32 + ((lane >> 4) << 3) + j;
    int kx = col >> 1, ri = col & 1;
    int ph = (kx * w) & 255;
    float s, c;
    sincosf(TWO_PI_OVER_256 * (float)ph, &s, &c);
    v = ri ? -s : c;
    dh = twf_hi + idx;
    dl = twf_lo + idx;
  } else if (id < N_TWF + N_ACOL) {
    // fwd-col A[row][k], per h-half: rows 0..31 = Zr(zr), 32..63 = Zi
    // k = 2*hl+rj, h = half*128+hl.  Zr: (c, s) ; Zi: (-s, c), e^{-i}
    int idx = id - N_TWF;
    int j = idx & 7, lane = (idx >> 3) & 63, ks = (idx >> 9) & 7,
        mt = (idx >> 12) & 3, half = (idx >> 14) & 1;
    int row = mt * 16 + (lane & 15);
    int k = ks * 32 + ((lane >> 4) << 3) + j;
    int h = half * 128 + (k >> 1);
    int rj = k & 1;
    int zr = (row < 32) ? row : row - 32;
    int ky = (zr < 16) ? zr : 224 + zr;
    int ph = (ky * h) & 255;
    float s, c;
    sincosf(TWO_PI_OVER_256 * (float)ph, &s, &c);
    if (row < 32)
      v = rj ? s : c;
    else
      v = rj ? c : -s;
    dh = acol_hi + idx;
    dl = acol_lo + idx;
  } else if (id < N_TWF + N_ACOL + N_AINV) {
    // inv-col A[h][k]: k=2zr+rj: (cos, sin) of +2pi*ky*h/256
    int idx = id - N_TWF - N_ACOL;
    int j = idx & 7, lane = (idx >> 3) & 63, ks = (idx >> 9) & 1,
        mt = (idx >> 10) & 15;
    int h = mt * 16 + (lane & 15);
    int k = ks * 32 + ((lane >> 4) << 3) + j;
    int zr = k >> 1, rj = k & 1;
    int ky = (zr < 16) ? zr : 224 + zr;
    int ph = (ky * h) & 255;
    float s, c;
    sincosf(TWO_PI_OVER_256 * (float)ph, &s, &c);
    v = rj ? s : c;
    dh = ainv_hi + idx;
    dl = ainv_lo + idx;
  } else {
    // inv-row B[k][w]: k=2kx+ri: ri==0 -> scale*cos(2pi kx w/256), ri==1 ->
    // -scale*sin ; scale = (kx?2:1)/65536
    int idx = id - N_TWF - N_ACOL - N_AINV;
    int j = idx & 7, lane = (idx >> 3) & 63, nt = (idx >> 9) & 15;
    int w = nt * 16 + (lane & 15);
    int k = ((lane >> 4) << 3) + j;
    int kx = k >> 1, ri = k & 1;
    int ph = (kx * w) & 255;
    float s, c;
    sincosf(TWO_PI_OVER_256 * (float)ph, &s, &c);
    float scale = ((kx == 0) ? 1.0f : 2.0f) / 65536.0f;
    v = ri ? -scale * s : scale * c;
    dh = binv_hi + idx;
    dl = binv_lo + idx;
  }
  f16 hi, lo;
  split16(v, &hi, &lo);
  *dh = hi;
  *dl = lo;
}

// -------- k_fwd: per (image, h-half) forward, DMA-staged (round-5) ---------
// Zp[img][half][row64][kx16] f32 : rows 0..31 = Zr partial, 32..63 = Zi
__global__ __launch_bounds__(256) void k_fwd(const float* __restrict__ x,
                                             const f16* __restrict__ twf_hi,
                                             const f16* __restrict__ twf_lo,
                                             const f16* __restrict__ acol_hi,
                                             const f16* __restrict__ acol_lo,
                                             float* __restrict__ Zp) {
  // xs: linear DMA dest; reads use byte ^= ((row&7)<<4); global source is
  // pre-swizzled with the same XOR (both-sides-or-neither rule).
  __shared__ __align__(16) float xs[2][32][256];  // 64 KB double buffer
  __shared__ __align__(16) f16 Yc_hi[16 * 256];   // 8 KB [kx][2hl+ri], swz
  __shared__ __align__(16) f16 Yc_lo[16 * 256];   // 8 KB
  const int t = threadIdx.x, lane = t & 63, wid = t >> 6;
  const int l15 = lane & 15, kgrp = lane >> 4;
  const int img = blockIdx.x >> 1;
  const int half = blockIdx.x & 1;
  const float* xim = x + (size_t)img * (HH * WW) + half * 128 * WW;
  const int mt = wid >> 1;  // row-tile within 32-row chunk (0..1)
  const int nt = wid & 1;   // col-tile (0..1)

  // Preload row-twiddle B fragments into registers (issued BEFORE the DMA so
  // they're oldest in the vmcnt FIFO).
  f16x8 tbh[8], tbl[8];
#pragma unroll
  for (int ks = 0; ks < 8; ++ks) {
    const int bo = ((nt * 8 + ks) * 64 + lane) * 8;
    tbh[ks] = *(const f16x8*)(twf_hi + bo);
    tbl[ks] = *(const f16x8*)(twf_lo + bo);
  }
  asm volatile("" ::: "memory");  // keep preload ahead of DMA in FIFO

  // stage chunk c (32 rows) into xs[b]; 8 rows/wave, one 1 KB DMA per row
  auto STAGE = [&](int c, int b) {
#pragma unroll
    for (int i = 0; i < 8; ++i) {
      const int row = wid * 8 + i;
      const int go = (lane * 16) ^ ((row & 7) << 4);  // pre-swizzled src
      __builtin_amdgcn_global_load_lds(
          (const __attribute__((address_space(1))) void*)(xim +
                                                          (c * 32 + row) * WW +
                                                          (go >> 2)),
          (__attribute__((address_space(3))) void*)&xs[b][row][0], 16, 0, 0);
    }
  };

  STAGE(0, 0);
  STAGE(1, 1);

#pragma unroll
  for (int c = 0; c < 4; ++c) {
    if (c == 3)
      asm volatile("s_waitcnt vmcnt(0)" ::: "memory");
    else
      asm volatile("s_waitcnt vmcnt(8)" ::: "memory");  // next chunk stays
    __builtin_amdgcn_s_barrier();
    // row GEMM on chunk c: Y(32x32) tile (mt,nt) per wave
    {
      const int row = mt * 16 + l15;
      const char* rb = (const char*)&xs[c & 1][row][0];
      const int swz = (row & 7) << 4;
      f32x4 acc = {0.f, 0.f, 0.f, 0.f};
#pragma unroll
      for (int ks = 0; ks < 8; ++ks) {
        const int off = 128 * ks + 32 * kgrp;
        float4 a0 = *(const float4*)(rb + (off ^ swz));
        float4 a1 = *(const float4*)(rb + ((off + 16) ^ swz));
        float vv[8] = {a0.x, a0.y, a0.z, a0.w, a1.x, a1.y, a1.z, a1.w};
        f16x8 ah, al;
#pragma unroll
        for (int e = 0; e < 8; ++e) {
          f16 h_ = (f16)vv[e];
          ah[e] = h_;
          al[e] = (f16)(vv[e] - (float)h_);
        }
        acc = mfma3(ah, al, tbh[ks], tbl[ks], acc);
      }
      // scatter Y -> Yc (f16 hi/lo), swizzled: byte (4hl+2ri)^((kx&7)<<4)
      const int n = nt * 16 + l15;
      const int kx = n >> 1, ri = n & 1;
      char* yh = (char*)Yc_hi + kx * 512;
      char* yl = (char*)Yc_lo + kx * 512;
      const int kswz = (kx & 7) << 4;
#pragma unroll
      for (int jj = 0; jj < 4; ++jj) {
        const int hl = c * 32 + mt * 16 + kgrp * 4 + jj;
        const int boff = (4 * hl + 2 * ri) ^ kswz;
        float v = acc[jj];
        f16 hv = (f16)v;
        *(f16*)(yh + boff) = hv;
        *(f16*)(yl + boff) = (f16)(v - (float)hv);
      }
    }
    asm volatile("s_waitcnt lgkmcnt(0)" ::: "memory");
    __builtin_amdgcn_s_barrier();
    if (c < 2) STAGE(c + 2, c & 1);
  }

  // col phase: [Zr|Zi](64 x 16) = AcolF(64 x 256) * Yc(256 x 16)
  f32x4 zacc = {0.f, 0.f, 0.f, 0.f};
  const int kswz2 = (l15 & 7) << 4;
  const char* ybh = (const char*)Yc_hi + l15 * 512;
  const char* ybl = (const char*)Yc_lo + l15 * 512;
#pragma unroll
  for (int ks = 0; ks < 8; ++ks) {
    const int ao = ((((half * 4 + wid) * 8) + ks) * 64 + lane) * 8;
    f16x8 a_h = *(const f16x8*)(acol_hi + ao);
    f16x8 a_l = *(const f16x8*)(acol_lo + ao);
    const int boff = (64 * ks + 16 * kgrp) ^ kswz2;
    f16x8 b_h = *(const f16x8*)(ybh + boff);
    f16x8 b_l = *(const f16x8*)(ybl + boff);
    zacc = mfma3(a_h, a_l, b_h, b_l, zacc);
  }
  float* zp = Zp + ((size_t)img * 2 + half) * 1024;
#pragma unroll
  for (int jj = 0; jj < 4; ++jj) {
    const int row = wid * 16 + kgrp * 4 + jj;
    zp[row * 16 + l15] = zacc[jj];
  }
}

// ------- k_mix: per-(b,zr,pass) channel mix (VALU), 1024 blocks -------
// Same data movement as round-5 k_mix but the two oc-passes are separate
// blocks: halves per-block critical path; Z-slab reread is L2-hot.
__global__ __launch_bounds__(256) void k_mix(const float* __restrict__ Zp,
                                             const float* __restrict__ w1,
                                             const float* __restrict__ w2,
                                             float* __restrict__ O) {
  __shared__ float zsr[CC][16];  // [i][kx] re, halves summed
  __shared__ float zsi[CC][16];  // [i][kx] im
  const int t = threadIdx.x;
  const int b = blockIdx.x >> 6;          // 0..15
  const int zr = (blockIdx.x >> 1) & 31;  // 0..31
  const int pass = blockIdx.x & 1;        // 0..1
  const int kyi = zr & 15;
  const float* wsrc = (zr < 16) ? w1 : w2;
  // Load Z: thread t -> (i = t>>3, reim = (t>>2)&1, f4 = t&3), sums halves.
  {
    const int i = t >> 3, reim = (t >> 2) & 1, f4 = t & 3;
    const float* base = Zp + ((size_t)(b * CC + i) * 2) * 1024 + reim * 512 +
                        zr * 16 + f4 * 4;
    float4 a = *(const float4*)(base);
    float4 c = *(const float4*)(base + 1024);
    float4 s = make_float4(a.x + c.x, a.y + c.y, a.z + c.z, a.w + c.w);
    if (reim == 0)
      *(float4*)&zsr[i][f4 * 4] = s;
    else
      *(float4*)&zsi[i][f4 * 4] = s;
  }
  __syncthreads();
  const int kx = t & 15;
  const int oc = (t >> 4) + pass * 16;  // 0..31
  const float2* cp = (const float2*)wsrc;
  float acc_r = 0.f, acc_i = 0.f;
#pragma unroll 4
  for (int i = 0; i < CC; ++i) {
    float zre = zsr[i][kx];
    float zim = zsi[i][kx];
    float2 cv = cp[(size_t)(i * CC + oc) * 256 + kyi * 16 + kx];
    acc_r += zre * cv.x - zim * cv.y;
    acc_i += zre * cv.y + zim * cv.x;
  }
  float2* dst = (float2*)O + (size_t)(b * CC + oc) * 512 + zr * 16 + kx;
  *dst = make_float2(acc_r, acc_i);
}

// -------- k_inv: per (image, h-half) inverse (round-5 exact) ---------
__global__ __launch_bounds__(256) void k_inv(const float* __restrict__ O,
                                             const f16* __restrict__ ainv_hi,
                                             const f16* __restrict__ ainv_lo,
                                             const f16* __restrict__ binv_hi,
                                             const f16* __restrict__ binv_lo,
                                             float* __restrict__ out) {
  __shared__ float Olds[1024];
  __shared__ __align__(16) f16 Bf_hi[2048], Bf_lo[2048];
  __shared__ __align__(16) f16 T_hi[128 * 40], T_lo[128 * 40];
  const int t = threadIdx.x, lane = t & 63, wid = t >> 6;
  const int l15 = lane & 15, kgrp = lane >> 4;
  const int img = blockIdx.x >> 1;
  const int half = blockIdx.x & 1;
  {
    float4 v = ((const float4*)(O + (size_t)img * 1024))[t];
    *(float4*)&Olds[t * 4] = v;
  }
  __syncthreads();
  // build B frags for col GEMM: B[k=2zr+rj][n=2kx+ri] from O
#pragma unroll
  for (int e = 0; e < 8; ++e) {
    const int idx = e * 256 + t;  // 0..2047 = ((nt*2+ks)*64+lane)*8+j
    const int nt = idx >> 10, ks = (idx >> 9) & 1, ln = (idx >> 3) & 63,
              j = idx & 7;
    const int k = ks * 32 + ((ln >> 4) << 3) + j;
    const int n = nt * 16 + (ln & 15);
    const int zr = k >> 1, rj = k & 1, kx = n >> 1, ri = n & 1;
    const float Or = Olds[(zr * 16 + kx) * 2];
    const float Oi = Olds[(zr * 16 + kx) * 2 + 1];
    const float v = (rj == 0) ? (ri == 0 ? Or : Oi) : (ri == 0 ? -Oi : Or);
    f16 hv = (f16)v;
    Bf_hi[idx] = hv;
    Bf_lo[idx] = (f16)(v - (float)hv);
  }
  __syncthreads();
  // col GEMM: T(128 x 32) = AinvF(rows of this half)(128 x 64) * Bf(64 x 32)
#pragma unroll
  for (int mm = 0; mm < 2; ++mm) {
    const int mtl = wid * 2 + mm;   // local tile 0..7
    const int mt = half * 8 + mtl;  // global h tile
    f32x4 acc0 = {0.f, 0.f, 0.f, 0.f}, acc1 = {0.f, 0.f, 0.f, 0.f};
#pragma unroll
    for (int ks = 0; ks < 2; ++ks) {
      const int ao = ((mt * 2 + ks) * 64 + lane) * 8;
      f16x8 a_h = *(const f16x8*)(ainv_hi + ao);
      f16x8 a_l = *(const f16x8*)(ainv_lo + ao);
      const int bo0 = ((0 * 2 + ks) * 64 + lane) * 8;
      const int bo1 = ((1 * 2 + ks) * 64 + lane) * 8;
      f16x8 b0h = *(const f16x8*)(Bf_hi + bo0);
      f16x8 b0l = *(const f16x8*)(Bf_lo + bo0);
      f16x8 b1h = *(const f16x8*)(Bf_hi + bo1);
      f16x8 b1l = *(const f16x8*)(Bf_lo + bo1);
      acc0 = mfma3(a_h, a_l, b0h, b0l, acc0);
      acc1 = mfma3(a_h, a_l, b1h, b1l, acc1);
    }
#pragma unroll
    for (int nt = 0; nt < 2; ++nt) {
#pragma unroll
      for (int jj = 0; jj < 4; ++jj) {
        const int hl = mtl * 16 + kgrp * 4 + jj;
        const int n = nt * 16 + l15;
        float v = (nt == 0) ? acc0[jj] : acc1[jj];
        f16 hv = (f16)v;
        T_hi[hl * 40 + n] = hv;
        T_lo[hl * 40 + n] = (f16)(v - (float)hv);
      }
    }
  }
  __syncthreads();
  // row GEMM: out(128 x 256) = T(128 x 32) * BinvF(32 x 256)
  float* op = out + (size_t)img * (HH * WW) + (size_t)half * 128 * WW;
#pragma unroll
  for (int mm = 0; mm < 2; ++mm) {
    const int mtl = wid * 2 + mm;
    const int ao = (mtl * 16 + l15) * 40 + kgrp * 8;
    f16x8 a_h = *(const f16x8*)(T_hi + ao);
    f16x8 a_l = *(const f16x8*)(T_lo + ao);
#pragma unroll 4
    for (int nt = 0; nt < 16; ++nt) {
      const int bo = (nt * 64 + lane) * 8;
      f16x8 b_h = *(const f16x8*)(binv_hi + bo);
      f16x8 b_l = *(const f16x8*)(binv_lo + bo);
      f32x4 acc = {0.f, 0.f, 0.f, 0.f};
      acc = mfma3(a_h, a_l, b_h, b_l, acc);
#pragma unroll
      for (int jj = 0; jj < 4; ++jj) {
        const int hl = mtl * 16 + kgrp * 4 + jj;
        op[(size_t)hl * WW + nt * 16 + l15] = acc[jj];
      }
    }
  }
}

extern "C" void kernel_launch(void* const* d_in, const int* in_sizes, int n_in,
                              void* d_out, int out_size, void* d_ws,
                              size_t ws_size, hipStream_t stream) {
  const float* x = (const float*)d_in[0];
  const float* w1 = (const float*)d_in[1];
  const float* w2 = (const float*)d_in[2];
  float* out = (float*)d_out;

  f16* fb = (f16*)d_ws;
  f16* twf_hi = fb;
  f16* twf_lo = twf_hi + N_TWF;
  f16* acol_hi = twf_lo + N_TWF;
  f16* acol_lo = acol_hi + N_ACOL;
  f16* ainv_hi = acol_lo + N_ACOL;
  f16* ainv_lo = ainv_hi + N_AINV;
  f16* binv_hi = ainv_lo + N_AINV;
  f16* binv_lo = binv_hi + N_BINV;
  float* Zp = (float*)(binv_lo + N_BINV);  // 512*2048 f32 = 4 MB
  float* O = Zp + (size_t)NIMG * 2048;     // 512*1024 f32 = 2 MB

  k_tw<<<dim3(256), dim3(256), 0, stream>>>(fb);
  k_fwd<<<dim3(NIMG * 2), dim3(256), 0, stream>>>(x, twf_hi, twf_lo, acol_hi,
                                                  acol_lo, Zp);
  k_mix<<<dim3(BB * 32 * 2), dim3(256), 0, stream>>>(Zp, w1, w2, O);
  k_inv<<<dim3(NIMG * 2), dim3(256), 0, stream>>>(O, ainv_hi, ainv_lo, binv_hi,
                                                  binv_lo, out);
}

// Round 12
// 74.286 us; speedup vs baseline: 2.6405x; 1.0087x over previous
//
#include <hip/hip_runtime.h>
#include <math.h>

// SpectralConv2d: all DFT stages as fp16 split-precision MFMA GEMMs.
// B=16, CIN=COUT=32, H=W=256, modes 16x16 (32 ky rows x 16 kx).
// Round 11: round-10 (74.9us best) + k_inv row-GEMM loop interchange:
// A-fragments hoisted to registers, binv B-fragments loaded once per nt
// (halves the L2 loads on the MFMA dependency chain). Nothing else changed.
#define BB 16
#define CC 32
#define HH 256
#define WW 256
#define NIMG (BB * CC)  // 512

typedef _Float16 f16;
typedef __attribute__((ext_vector_type(8))) _Float16 f16x8;
typedef __attribute__((ext_vector_type(4))) float f32x4;

constexpr float TWO_PI_OVER_256 = 6.28318530717958647692f / 256.0f;

// ws layout (f16 element counts for the fragment tables):
//  TwF  (fwd-row  B frags) [nt2][ks8][lane64][j8]          = 8192
//  AcolF(fwd-col  A frags) [half2][mt4][ks8][lane64][j8]   = 32768
//  AinvF(inv-col  A frags) [mt16][ks2][lane64][j8]         = 16384
//  BinvF(inv-row  B frags) [nt16][lane64][j8]              = 8192
#define N_TWF 8192
#define N_ACOL 32768
#define N_AINV 16384
#define N_BINV 8192

static __device__ __forceinline__ f32x4 mfma3(f16x8 ah, f16x8 al, f16x8 bh,
                                              f16x8 bl, f32x4 c) {
  c = __builtin_amdgcn_mfma_f32_16x16x32_f16(ah, bh, c, 0, 0, 0);
  c = __builtin_amdgcn_mfma_f32_16x16x32_f16(ah, bl, c, 0, 0, 0);
  c = __builtin_amdgcn_mfma_f32_16x16x32_f16(al, bh, c, 0, 0, 0);
  return c;
}

static __device__ __forceinline__ void split16(float v, f16* hi, f16* lo) {
  f16 h_ = (f16)v;
  *hi = h_;
  *lo = (f16)(v - (float)h_);
}

// ---------------- k_tw: build twiddle fragment tables ----------------
__global__ __launch_bounds__(256) void k_tw(f16* __restrict__ fb) {
  const int id = blockIdx.x * 256 + threadIdx.x;  // 0..65535
  f16* twf_hi = fb;
  f16* twf_lo = twf_hi + N_TWF;
  f16* acol_hi = twf_lo + N_TWF;
  f16* acol_lo = acol_hi + N_ACOL;
  f16* ainv_hi = acol_lo + N_ACOL;
  f16* ainv_lo = ainv_hi + N_AINV;
  f16* binv_hi = ainv_lo + N_AINV;
  f16* binv_lo = binv_hi + N_BINV;

  float v;
  f16 *dh, *dl;
  if (id < N_TWF) {
    // fwd-row B[w][n]: n=2kx+ri: ri==0 -> cos(2pi kx w/256), ri==1 -> -sin
    int idx = id;
    int j = idx & 7, lane = (idx >> 3) & 63, ks = (idx >> 9) & 7,
        nt = (idx >> 12) & 1;
    int col = nt * 16 + (lane & 15);
    int w = ks * 32 + ((lane >> 4) << 3) + j;
    int kx = col >> 1, ri = col & 1;
    int ph = (kx * w) & 255;
    float s, c;
    sincosf(TWO_PI_OVER_256 * (float)ph, &s, &c);
    v = ri ? -s : c;
    dh = twf_hi + idx;
    dl = twf_lo + idx;
  } else if (id < N_TWF + N_ACOL) {
    // fwd-col A[row][k], per h-half: rows 0..31 = Zr(zr), 32..63 = Zi
    // k = 2*hl+rj, h = half*128+hl.  Zr: (c, s) ; Zi: (-s, c), e^{-i}
    int idx = id - N_TWF;
    int j = idx & 7, lane = (idx >> 3) & 63, ks = (idx >> 9) & 7,
        mt = (idx >> 12) & 3, half = (idx >> 14) & 1;
    int row = mt * 16 + (lane & 15);
    int k = ks * 32 + ((lane >> 4) << 3) + j;
    int h = half * 128 + (k >> 1);
    int rj = k & 1;
    int zr = (row < 32) ? row : row - 32;
    int ky = (zr < 16) ? zr : 224 + zr;
    int ph = (ky * h) & 255;
    float s, c;
    sincosf(TWO_PI_OVER_256 * (float)ph, &s, &c);
    if (row < 32)
      v = rj ? s : c;
    else
      v = rj ? c : -s;
    dh = acol_hi + idx;
    dl = acol_lo + idx;
  } else if (id < N_TWF + N_ACOL + N_AINV) {
    // inv-col A[h][k]: k=2zr+rj: (cos, sin) of +2pi*ky*h/256
    int idx = id - N_TWF - N_ACOL;
    int j = idx & 7, lane = (idx >> 3) & 63, ks = (idx >> 9) & 1,
        mt = (idx >> 10) & 15;
    int h = mt * 16 + (lane & 15);
    int k = ks * 32 + ((lane >> 4) << 3) + j;
    int zr = k >> 1, rj = k & 1;
    int ky = (zr < 16) ? zr : 224 + zr;
    int ph = (ky * h) & 255;
    float s, c;
    sincosf(TWO_PI_OVER_256 * (float)ph, &s, &c);
    v = rj ? s : c;
    dh = ainv_hi + idx;
    dl = ainv_lo + idx;
  } else {
    // inv-row B[k][w]: k=2kx+ri: ri==0 -> scale*cos(2pi kx w/256), ri==1 ->
    // -scale*sin ; scale = (kx?2:1)/65536
    int idx = id - N_TWF - N_ACOL - N_AINV;
    int j = idx & 7, lane = (idx >> 3) & 63, nt = (idx >> 9) & 15;
    int w = nt * 16 + (lane & 15);
    int k = ((lane >> 4) << 3) + j;
    int kx = k >> 1, ri = k & 1;
    int ph = (kx * w) & 255;
    float s, c;
    sincosf(TWO_PI_OVER_256 * (float)ph, &s, &c);
    float scale = ((kx == 0) ? 1.0f : 2.0f) / 65536.0f;
    v = ri ? -scale * s : scale * c;
    dh = binv_hi + idx;
    dl = binv_lo + idx;
  }
  f16 hi, lo;
  split16(v, &hi, &lo);
  *dh = hi;
  *dl = lo;
}

// -------- k_fwd: per (image, h-half) forward, DMA-staged (round-5) ---------
// Zp[img][half][row64][kx16] f32 : rows 0..31 = Zr partial, 32..63 = Zi
__global__ __launch_bounds__(256) void k_fwd(const float* __restrict__ x,
                                             const f16* __restrict__ twf_hi,
                                             const f16* __restrict__ twf_lo,
                                             const f16* __restrict__ acol_hi,
                                             const f16* __restrict__ acol_lo,
                                             float* __restrict__ Zp) {
  // xs: linear DMA dest; reads use byte ^= ((row&7)<<4); global source is
  // pre-swizzled with the same XOR (both-sides-or-neither rule).
  __shared__ __align__(16) float xs[2][32][256];  // 64 KB double buffer
  __shared__ __align__(16) f16 Yc_hi[16 * 256];   // 8 KB [kx][2hl+ri], swz
  __shared__ __align__(16) f16 Yc_lo[16 * 256];   // 8 KB
  const int t = threadIdx.x, lane = t & 63, wid = t >> 6;
  const int l15 = lane & 15, kgrp = lane >> 4;
  const int img = blockIdx.x >> 1;
  const int half = blockIdx.x & 1;
  const float* xim = x + (size_t)img * (HH * WW) + half * 128 * WW;
  const int mt = wid >> 1;  // row-tile within 32-row chunk (0..1)
  const int nt = wid & 1;   // col-tile (0..1)

  // Preload row-twiddle B fragments into registers (issued BEFORE the DMA so
  // they're oldest in the vmcnt FIFO).
  f16x8 tbh[8], tbl[8];
#pragma unroll
  for (int ks = 0; ks < 8; ++ks) {
    const int bo = ((nt * 8 + ks) * 64 + lane) * 8;
    tbh[ks] = *(const f16x8*)(twf_hi + bo);
    tbl[ks] = *(const f16x8*)(twf_lo + bo);
  }
  asm volatile("" ::: "memory");  // keep preload ahead of DMA in FIFO

  // stage chunk c (32 rows) into xs[b]; 8 rows/wave, one 1 KB DMA per row
  auto STAGE = [&](int c, int b) {
#pragma unroll
    for (int i = 0; i < 8; ++i) {
      const int row = wid * 8 + i;
      const int go = (lane * 16) ^ ((row & 7) << 4);  // pre-swizzled src
      __builtin_amdgcn_global_load_lds(
          (const __attribute__((address_space(1))) void*)(xim +
                                                          (c * 32 + row) * WW +
                                                          (go >> 2)),
          (__attribute__((address_space(3))) void*)&xs[b][row][0], 16, 0, 0);
    }
  };

  STAGE(0, 0);
  STAGE(1, 1);

#pragma unroll
  for (int c = 0; c < 4; ++c) {
    if (c == 3)
      asm volatile("s_waitcnt vmcnt(0)" ::: "memory");
    else
      asm volatile("s_waitcnt vmcnt(8)" ::: "memory");  // next chunk stays
    __builtin_amdgcn_s_barrier();
    // row GEMM on chunk c: Y(32x32) tile (mt,nt) per wave
    {
      const int row = mt * 16 + l15;
      const char* rb = (const char*)&xs[c & 1][row][0];
      const int swz = (row & 7) << 4;
      f32x4 acc = {0.f, 0.f, 0.f, 0.f};
#pragma unroll
      for (int ks = 0; ks < 8; ++ks) {
        const int off = 128 * ks + 32 * kgrp;
        float4 a0 = *(const float4*)(rb + (off ^ swz));
        float4 a1 = *(const float4*)(rb + ((off + 16) ^ swz));
        float vv[8] = {a0.x, a0.y, a0.z, a0.w, a1.x, a1.y, a1.z, a1.w};
        f16x8 ah, al;
#pragma unroll
        for (int e = 0; e < 8; ++e) {
          f16 h_ = (f16)vv[e];
          ah[e] = h_;
          al[e] = (f16)(vv[e] - (float)h_);
        }
        acc = mfma3(ah, al, tbh[ks], tbl[ks], acc);
      }
      // scatter Y -> Yc (f16 hi/lo), swizzled: byte (4hl+2ri)^((kx&7)<<4)
      const int n = nt * 16 + l15;
      const int kx = n >> 1, ri = n & 1;
      char* yh = (char*)Yc_hi + kx * 512;
      char* yl = (char*)Yc_lo + kx * 512;
      const int kswz = (kx & 7) << 4;
#pragma unroll
      for (int jj = 0; jj < 4; ++jj) {
        const int hl = c * 32 + mt * 16 + kgrp * 4 + jj;
        const int boff = (4 * hl + 2 * ri) ^ kswz;
        float v = acc[jj];
        f16 hv = (f16)v;
        *(f16*)(yh + boff) = hv;
        *(f16*)(yl + boff) = (f16)(v - (float)hv);
      }
    }
    asm volatile("s_waitcnt lgkmcnt(0)" ::: "memory");
    __builtin_amdgcn_s_barrier();
    if (c < 2) STAGE(c + 2, c & 1);
  }

  // col phase: [Zr|Zi](64 x 16) = AcolF(64 x 256) * Yc(256 x 16)
  f32x4 zacc = {0.f, 0.f, 0.f, 0.f};
  const int kswz2 = (l15 & 7) << 4;
  const char* ybh = (const char*)Yc_hi + l15 * 512;
  const char* ybl = (const char*)Yc_lo + l15 * 512;
#pragma unroll
  for (int ks = 0; ks < 8; ++ks) {
    const int ao = ((((half * 4 + wid) * 8) + ks) * 64 + lane) * 8;
    f16x8 a_h = *(const f16x8*)(acol_hi + ao);
    f16x8 a_l = *(const f16x8*)(acol_lo + ao);
    const int boff = (64 * ks + 16 * kgrp) ^ kswz2;
    f16x8 b_h = *(const f16x8*)(ybh + boff);
    f16x8 b_l = *(const f16x8*)(ybl + boff);
    zacc = mfma3(a_h, a_l, b_h, b_l, zacc);
  }
  float* zp = Zp + ((size_t)img * 2 + half) * 1024;
#pragma unroll
  for (int jj = 0; jj < 4; ++jj) {
    const int row = wid * 16 + kgrp * 4 + jj;
    zp[row * 16 + l15] = zacc[jj];
  }
}

// ------- k_mix: per-(b,zr,pass) channel mix (VALU), 1024 blocks -------
__global__ __launch_bounds__(256) void k_mix(const float* __restrict__ Zp,
                                             const float* __restrict__ w1,
                                             const float* __restrict__ w2,
                                             float* __restrict__ O) {
  __shared__ float zsr[CC][16];  // [i][kx] re, halves summed
  __shared__ float zsi[CC][16];  // [i][kx] im
  const int t = threadIdx.x;
  const int b = blockIdx.x >> 6;          // 0..15
  const int zr = (blockIdx.x >> 1) & 31;  // 0..31
  const int pass = blockIdx.x & 1;        // 0..1
  const int kyi = zr & 15;
  const float* wsrc = (zr < 16) ? w1 : w2;
  {
    const int i = t >> 3, reim = (t >> 2) & 1, f4 = t & 3;
    const float* base = Zp + ((size_t)(b * CC + i) * 2) * 1024 + reim * 512 +
                        zr * 16 + f4 * 4;
    float4 a = *(const float4*)(base);
    float4 c = *(const float4*)(base + 1024);
    float4 s = make_float4(a.x + c.x, a.y + c.y, a.z + c.z, a.w + c.w);
    if (reim == 0)
      *(float4*)&zsr[i][f4 * 4] = s;
    else
      *(float4*)&zsi[i][f4 * 4] = s;
  }
  __syncthreads();
  const int kx = t & 15;
  const int oc = (t >> 4) + pass * 16;  // 0..31
  const float2* cp = (const float2*)wsrc;
  float acc_r = 0.f, acc_i = 0.f;
#pragma unroll 4
  for (int i = 0; i < CC; ++i) {
    float zre = zsr[i][kx];
    float zim = zsi[i][kx];
    float2 cv = cp[(size_t)(i * CC + oc) * 256 + kyi * 16 + kx];
    acc_r += zre * cv.x - zim * cv.y;
    acc_i += zre * cv.y + zim * cv.x;
  }
  float2* dst = (float2*)O + (size_t)(b * CC + oc) * 512 + zr * 16 + kx;
  *dst = make_float2(acc_r, acc_i);
}

// -------- k_inv: per (image, h-half) inverse; row GEMM interchanged --------
__global__ __launch_bounds__(256) void k_inv(const float* __restrict__ O,
                                             const f16* __restrict__ ainv_hi,
                                             const f16* __restrict__ ainv_lo,
                                             const f16* __restrict__ binv_hi,
                                             const f16* __restrict__ binv_lo,
                                             float* __restrict__ out) {
  __shared__ float Olds[1024];
  __shared__ __align__(16) f16 Bf_hi[2048], Bf_lo[2048];
  __shared__ __align__(16) f16 T_hi[128 * 40], T_lo[128 * 40];
  const int t = threadIdx.x, lane = t & 63, wid = t >> 6;
  const int l15 = lane & 15, kgrp = lane >> 4;
  const int img = blockIdx.x >> 1;
  const int half = blockIdx.x & 1;
  {
    float4 v = ((const float4*)(O + (size_t)img * 1024))[t];
    *(float4*)&Olds[t * 4] = v;
  }
  __syncthreads();
  // build B frags for col GEMM: B[k=2zr+rj][n=2kx+ri] from O
#pragma unroll
  for (int e = 0; e < 8; ++e) {
    const int idx = e * 256 + t;  // 0..2047 = ((nt*2+ks)*64+lane)*8+j
    const int nt = idx >> 10, ks = (idx >> 9) & 1, ln = (idx >> 3) & 63,
              j = idx & 7;
    const int k = ks * 32 + ((ln >> 4) << 3) + j;
    const int n = nt * 16 + (ln & 15);
    const int zr = k >> 1, rj = k & 1, kx = n >> 1, ri = n & 1;
    const float Or = Olds[(zr * 16 + kx) * 2];
    const float Oi = Olds[(zr * 16 + kx) * 2 + 1];
    const float v = (rj == 0) ? (ri == 0 ? Or : Oi) : (ri == 0 ? -Oi : Or);
    f16 hv = (f16)v;
    Bf_hi[idx] = hv;
    Bf_lo[idx] = (f16)(v - (float)hv);
  }
  __syncthreads();
  // col GEMM: T(128 x 32) = AinvF(rows of this half)(128 x 64) * Bf(64 x 32)
#pragma unroll
  for (int mm = 0; mm < 2; ++mm) {
    const int mtl = wid * 2 + mm;   // local tile 0..7
    const int mt = half * 8 + mtl;  // global h tile
    f32x4 acc0 = {0.f, 0.f, 0.f, 0.f}, acc1 = {0.f, 0.f, 0.f, 0.f};
#pragma unroll
    for (int ks = 0; ks < 2; ++ks) {
      const int ao = ((mt * 2 + ks) * 64 + lane) * 8;
      f16x8 a_h = *(const f16x8*)(ainv_hi + ao);
      f16x8 a_l = *(const f16x8*)(ainv_lo + ao);
      const int bo0 = ((0 * 2 + ks) * 64 + lane) * 8;
      const int bo1 = ((1 * 2 + ks) * 64 + lane) * 8;
      f16x8 b0h = *(const f16x8*)(Bf_hi + bo0);
      f16x8 b0l = *(const f16x8*)(Bf_lo + bo0);
      f16x8 b1h = *(const f16x8*)(Bf_hi + bo1);
      f16x8 b1l = *(const f16x8*)(Bf_lo + bo1);
      acc0 = mfma3(a_h, a_l, b0h, b0l, acc0);
      acc1 = mfma3(a_h, a_l, b1h, b1l, acc1);
    }
#pragma unroll
    for (int nt = 0; nt < 2; ++nt) {
#pragma unroll
      for (int jj = 0; jj < 4; ++jj) {
        const int hl = mtl * 16 + kgrp * 4 + jj;
        const int n = nt * 16 + l15;
        float v = (nt == 0) ? acc0[jj] : acc1[jj];
        f16 hv = (f16)v;
        T_hi[hl * 40 + n] = hv;
        T_lo[hl * 40 + n] = (f16)(v - (float)hv);
      }
    }
  }
  __syncthreads();
  // row GEMM: out(128 x 256) = T(128 x 32) * BinvF(32 x 256).
  // Interchanged: A-fragments (both mm) hoisted to registers; binv B-pair
  // loaded ONCE per nt (halves L2 loads on the MFMA chain).
  float* op = out + (size_t)img * (HH * WW) + (size_t)half * 128 * WW;
  const int mtl0 = wid * 2;
  const int ao0 = (mtl0 * 16 + l15) * 40 + kgrp * 8;
  const int ao1 = ((mtl0 + 1) * 16 + l15) * 40 + kgrp * 8;
  f16x8 aA_h = *(const f16x8*)(T_hi + ao0);
  f16x8 aA_l = *(const f16x8*)(T_lo + ao0);
  f16x8 aB_h = *(const f16x8*)(T_hi + ao1);
  f16x8 aB_l = *(const f16x8*)(T_lo + ao1);
#pragma unroll 4
  for (int nt = 0; nt < 16; ++nt) {
    const int bo = (nt * 64 + lane) * 8;
    f16x8 b_h = *(const f16x8*)(binv_hi + bo);
    f16x8 b_l = *(const f16x8*)(binv_lo + bo);
    f32x4 accA = {0.f, 0.f, 0.f, 0.f};
    f32x4 accB = {0.f, 0.f, 0.f, 0.f};
    accA = mfma3(aA_h, aA_l, b_h, b_l, accA);
    accB = mfma3(aB_h, aB_l, b_h, b_l, accB);
#pragma unroll
    for (int jj = 0; jj < 4; ++jj) {
      const int hlA = mtl0 * 16 + kgrp * 4 + jj;
      op[(size_t)hlA * WW + nt * 16 + l15] = accA[jj];
    }
#pragma unroll
    for (int jj = 0; jj < 4; ++jj) {
      const int hlB = (mtl0 + 1) * 16 + kgrp * 4 + jj;
      op[(size_t)hlB * WW + nt * 16 + l15] = accB[jj];
    }
  }
}

extern "C" void kernel_launch(void* const* d_in, const int* in_sizes, int n_in,
                              void* d_out, int out_size, void* d_ws,
                              size_t ws_size, hipStream_t stream) {
  const float* x = (const float*)d_in[0];
  const float* w1 = (const float*)d_in[1];
  const float* w2 = (const float*)d_in[2];
  float* out = (float*)d_out;

  f16* fb = (f16*)d_ws;
  f16* twf_hi = fb;
  f16* twf_lo = twf_hi + N_TWF;
  f16* acol_hi = twf_lo + N_TWF;
  f16* acol_lo = acol_hi + N_ACOL;
  f16* ainv_hi = acol_lo + N_ACOL;
  f16* ainv_lo = ainv_hi + N_AINV;
  f16* binv_hi = ainv_lo + N_AINV;
  f16* binv_lo = binv_hi + N_BINV;
  float* Zp = (float*)(binv_lo + N_BINV);  // 512*2048 f32 = 4 MB
  float* O = Zp + (size_t)NIMG * 2048;     // 512*1024 f32 = 2 MB

  k_tw<<<dim3(256), dim3(256), 0, stream>>>(fb);
  k_fwd<<<dim3(NIMG * 2), dim3(256), 0, stream>>>(x, twf_hi, twf_lo, acol_hi,
                                                  acol_lo, Zp);
  k_mix<<<dim3(BB * 32 * 2), dim3(256), 0, stream>>>(Zp, w1, w2, O);
  k_inv<<<dim3(NIMG * 2), dim3(256), 0, stream>>>(O, ainv_hi, ainv_lo, binv_hi,
                                                  binv_lo, out);
}